// Round 2
// baseline (411.824 us; speedup 1.0000x reference)
//
#include <hip/hip_runtime.h>

typedef _Float16 f16;
typedef _Float16 f16x4 __attribute__((ext_vector_type(4)));
typedef _Float16 f16x8 __attribute__((ext_vector_type(8)));
typedef float f32x4 __attribute__((ext_vector_type(4)));

#define AS1(p) ((const __attribute__((address_space(1))) void*)(p))
#define AS3(p) ((__attribute__((address_space(3))) void*)(p))

// ---------------- conversion kernels ----------------

// generic fp32 -> fp16, n4 float4s
__global__ void conv_f32_to_f16(const float* __restrict__ src, f16* __restrict__ dst, long n4) {
  long i = (long)blockIdx.x * blockDim.x + threadIdx.x;
  if (i >= n4) return;
  const float4 v = ((const float4*)src)[i];
  f16x4 o = { (f16)v.x, (f16)v.y, (f16)v.z, (f16)v.w };
  ((f16x4*)dst)[i] = o;
}

// tokens: src [B, rpb, 1024] fp32 -> dst[b*1024*1024 + dstOff + r*1024 + e] fp16
__global__ void conv_tokens(const float* __restrict__ src, f16* __restrict__ dst,
                            int rpb, long dstOff, long n4) {
  long i = (long)blockIdx.x * blockDim.x + threadIdx.x;
  if (i >= n4) return;
  long perB = (long)rpb * 256;  // float4s per batch
  long b = i / perB, off = i % perB;
  const float4 v = ((const float4*)src)[i];
  f16x4 o = { (f16)v.x, (f16)v.y, (f16)v.z, (f16)v.w };
  ((f16x4*)(dst + b * 1024 * 1024 + dstOff))[off] = o;
}

// ---------------- GEMM: C[M,N] = A[M,K] @ B[N,K]^T ----------------
// 128x128 tile, BK=32, 256 threads (4 waves, 2x2 of 64x64), m97 structure.
// OUTF: 0 = f16 store, 1 = f16 store * scale, 2 = f32 store + bias
template<int OUTF>
__global__ __launch_bounds__(256)
void gemm_bt(const f16* __restrict__ A, const f16* __restrict__ Bw,
             void* __restrict__ Cv, const float* __restrict__ bias,
             int M, long sA, long sB, long sC, float scale)
{
  constexpr int K = 1024, N = 1024;
  __shared__ f16 lA[128 * 32];
  __shared__ f16 lB[128 * 32];
  const int bz = blockIdx.z;
  A += (long)bz * sA;
  Bw += (long)bz * sB;
  const int t = threadIdx.x;
  const int w = t >> 6;
  const int l = t & 63;
  const int wr = w >> 1, wc = w & 1;
  const int mrow0 = blockIdx.y * 128;
  const int ncol0 = blockIdx.x * 128;

  f32x4 acc[4][4] = {};

  const int r16 = l & 15;
  const int kb = (l >> 4) * 8;

  for (int kt = 0; kt < K / 32; ++kt) {
    // stage A,B tiles: each thread 2x16B per operand
    #pragma unroll
    for (int i = 0; i < 2; ++i) {
      int ar = mrow0 + i * 64 + (t >> 2);
      if (ar >= M) ar = M - 1;              // clamp (store is guarded)
      const f16* ga = A + (long)ar * K + kt * 32 + (t & 3) * 8;
      __builtin_amdgcn_global_load_lds(AS1(ga), AS3(&lA[i * 2048 + t * 8]), 16, 0, 0);
      int br = ncol0 + i * 64 + (t >> 2);   // N==1024 always full
      const f16* gb = Bw + (long)br * K + kt * 32 + (t & 3) * 8;
      __builtin_amdgcn_global_load_lds(AS1(gb), AS3(&lB[i * 2048 + t * 8]), 16, 0, 0);
    }
    __syncthreads();

    f16x8 af[4], bf[4];
    #pragma unroll
    for (int m = 0; m < 4; ++m)
      af[m] = *(const f16x8*)&lA[(wr * 64 + m * 16 + r16) * 32 + kb];
    #pragma unroll
    for (int n = 0; n < 4; ++n)
      bf[n] = *(const f16x8*)&lB[(wc * 64 + n * 16 + r16) * 32 + kb];

    #pragma unroll
    for (int m = 0; m < 4; ++m)
      #pragma unroll
      for (int n = 0; n < 4; ++n)
        acc[m][n] = __builtin_amdgcn_mfma_f32_16x16x32_f16(af[m], bf[n], acc[m][n], 0, 0, 0);

    __syncthreads();
  }

  // epilogue: C/D layout col = lane&15, row = (lane>>4)*4 + reg
  const int rj = (l >> 4) * 4;
  #pragma unroll
  for (int m = 0; m < 4; ++m) {
    #pragma unroll
    for (int j = 0; j < 4; ++j) {
      int r = mrow0 + wr * 64 + m * 16 + rj + j;
      if (r >= M) continue;
      #pragma unroll
      for (int n = 0; n < 4; ++n) {
        int c = ncol0 + wc * 64 + n * 16 + r16;
        float v = acc[m][n][j];
        if constexpr (OUTF == 0) {
          ((f16*)Cv)[(long)bz * sC + (long)r * N + c] = (f16)v;
        } else if constexpr (OUTF == 1) {
          ((f16*)Cv)[(long)bz * sC + (long)r * N + c] = (f16)(v * scale);
        } else {
          ((float*)Cv)[(long)bz * sC + (long)r * N + c] = v + bias[c];
        }
      }
    }
  }
}

// ---------------- row softmax, in-place on fp16 [B*S, 1024] ----------------
__global__ __launch_bounds__(256)
void softmax_rows(f16* __restrict__ S) {
  const long row = blockIdx.x;
  f16* p = S + row * 1024;
  const int t = threadIdx.x;
  f16x4 v4 = ((f16x4*)p)[t];
  float v[4];
  #pragma unroll
  for (int j = 0; j < 4; ++j) v[j] = (float)v4[j];

  float m = fmaxf(fmaxf(v[0], v[1]), fmaxf(v[2], v[3]));
  #pragma unroll
  for (int off = 1; off < 64; off <<= 1) m = fmaxf(m, __shfl_xor(m, off));
  __shared__ float sm[4], ss[4];
  const int w = t >> 6;
  if ((t & 63) == 0) sm[w] = m;
  __syncthreads();
  m = fmaxf(fmaxf(sm[0], sm[1]), fmaxf(sm[2], sm[3]));

  float e[4], s = 0.f;
  #pragma unroll
  for (int j = 0; j < 4; ++j) { e[j] = __expf(v[j] - m); s += e[j]; }
  #pragma unroll
  for (int off = 1; off < 64; off <<= 1) s += __shfl_xor(s, off);
  if ((t & 63) == 0) ss[w] = s;
  __syncthreads();
  s = ss[0] + ss[1] + ss[2] + ss[3];
  const float inv = 1.f / s;

  f16x4 o;
  #pragma unroll
  for (int j = 0; j < 4; ++j) o[j] = (f16)(e[j] * inv);
  ((f16x4*)p)[t] = o;
}

// ---------------- per-batch 1024x1024 fp16 transpose ----------------
__global__ void transpose_f16(const f16* __restrict__ in, f16* __restrict__ out) {
  __shared__ f16 tile[32][33];
  const long bs = (long)blockIdx.z * 1024 * 1024;
  const int r0 = blockIdx.y * 32, c0 = blockIdx.x * 32;
  const int tx = threadIdx.x, ty = threadIdx.y;  // (32, 8)
  #pragma unroll
  for (int i = 0; i < 4; ++i)
    tile[ty + 8 * i][tx] = in[bs + (long)(r0 + ty + 8 * i) * 1024 + c0 + tx];
  __syncthreads();
  #pragma unroll
  for (int i = 0; i < 4; ++i)
    out[bs + (long)(c0 + ty + 8 * i) * 1024 + r0 + tx] = tile[tx][ty + 8 * i];
}

// ---------------- launch ----------------
extern "C" void kernel_launch(void* const* d_in, const int* in_sizes, int n_in,
                              void* d_out, int out_size, void* d_ws, size_t ws_size,
                              hipStream_t stream) {
  const float* vis = (const float*)d_in[0];  // [16,576,1024]
  const float* lan = (const float*)d_in[1];  // [16,448,1024]
  const float* Wv  = (const float*)d_in[2];  // [1024,1024]
  const float* Wl  = (const float*)d_in[3];
  const float* Wo  = (const float*)d_in[4];
  const float* bo  = (const float*)d_in[5];  // [1024]
  float* out = (float*)d_out;                // [16,1024,1024] fp32

  const long PB = 1024l * 1024;  // per-batch elements
  const long SE = 16 * PB;       // full tensor elements

  f16* Ah  = (f16*)d_ws;         // concat fp16 tokens  [16,1024,1024]
  f16* Xh  = Ah + SE;            // projected X fp16
  f16* Sc  = Xh + SE;            // scores / P fp16
  f16* Wvh = Sc + SE;
  f16* Wlh = Wvh + PB;
  f16* Woh = Wlh + PB;
  f16* XhT = Ah;                 // alias: Ah dead after projections
  f16* Att = Xh;                 // alias: Xh dead after transpose+scores

  // 1) convert tokens into concatenated fp16 buffer
  {
    long n4 = 16l * 576 * 1024 / 4;
    conv_tokens<<<dim3((n4 + 255) / 256), 256, 0, stream>>>(vis, Ah, 576, 0, n4);
  }
  {
    long n4 = 16l * 448 * 1024 / 4;
    conv_tokens<<<dim3((n4 + 255) / 256), 256, 0, stream>>>(lan, Ah, 448, 576l * 1024, n4);
  }
  // 2) convert weights
  {
    long n4 = PB / 4;
    conv_f32_to_f16<<<dim3((n4 + 255) / 256), 256, 0, stream>>>(Wv, Wvh, n4);
    conv_f32_to_f16<<<dim3((n4 + 255) / 256), 256, 0, stream>>>(Wl, Wlh, n4);
    conv_f32_to_f16<<<dim3((n4 + 255) / 256), 256, 0, stream>>>(Wo, Woh, n4);
  }
  // 3) projections: X = tokens @ W^T  (vision rows 0..575, language rows 576..1023)
  gemm_bt<0><<<dim3(8, 5, 16), 256, 0, stream>>>(Ah, Wvh, Xh, nullptr, 576, PB, 0, PB, 1.f);
  gemm_bt<0><<<dim3(8, 4, 16), 256, 0, stream>>>(Ah + 576l * 1024, Wlh, Xh + 576l * 1024,
                                                 nullptr, 448, PB, 0, PB, 1.f);
  // 4) scores = (X @ X^T) / 32, fp16
  gemm_bt<1><<<dim3(8, 8, 16), 256, 0, stream>>>(Xh, Xh, Sc, nullptr, 1024, PB, PB, PB,
                                                 0.03125f);
  // 5) transpose X (before softmax so Xh alias for Att stays clean ordering-wise)
  transpose_f16<<<dim3(32, 32, 16), dim3(32, 8), 0, stream>>>(Xh, XhT);
  // 6) softmax rows in place
  softmax_rows<<<dim3(16 * 1024), 256, 0, stream>>>(Sc);
  // 7) attended = P @ X  (as P @ (X^T)^T via gemm_bt with B = XhT)
  gemm_bt<0><<<dim3(8, 8, 16), 256, 0, stream>>>(Sc, XhT, Att, nullptr, 1024, PB, PB, PB, 1.f);
  // 8) out = attended @ Wo^T + bo, fp32, flattened M = 16384
  gemm_bt<2><<<dim3(8, 128, 1), 256, 0, stream>>>(Att, Woh, out, bo, 16384, 0, 0, 0, 1.f);
}

// Round 3
// 355.242 us; speedup vs baseline: 1.1593x; 1.1593x over previous
//
#include <hip/hip_runtime.h>

typedef _Float16 f16;
typedef _Float16 f16x4 __attribute__((ext_vector_type(4)));
typedef _Float16 f16x8 __attribute__((ext_vector_type(8)));
typedef float f32x4 __attribute__((ext_vector_type(4)));

#define AS1(p) ((const __attribute__((address_space(1))) void*)(p))
#define AS3(p) ((__attribute__((address_space(3))) void*)(p))
#define BAR() { asm volatile("" ::: "memory"); __builtin_amdgcn_s_barrier(); \
                asm volatile("" ::: "memory"); __builtin_amdgcn_sched_barrier(0); }
#define VMCNT(n) asm volatile("s_waitcnt vmcnt(" #n ")" ::: "memory")

// ---------------- conversion kernels ----------------

__global__ void conv_f32_to_f16(const float* __restrict__ src, f16* __restrict__ dst, long n4) {
  long i = (long)blockIdx.x * blockDim.x + threadIdx.x;
  if (i >= n4) return;
  const float4 v = ((const float4*)src)[i];
  f16x4 o = { (f16)v.x, (f16)v.y, (f16)v.z, (f16)v.w };
  ((f16x4*)dst)[i] = o;
}

__global__ void conv_tokens(const float* __restrict__ src, f16* __restrict__ dst,
                            int rpb, long dstOff, long n4) {
  long i = (long)blockIdx.x * blockDim.x + threadIdx.x;
  if (i >= n4) return;
  long perB = (long)rpb * 256;
  long b = i / perB, off = i % perB;
  const float4 v = ((const float4*)src)[i];
  f16x4 o = { (f16)v.x, (f16)v.y, (f16)v.z, (f16)v.w };
  ((f16x4*)(dst + b * 1024 * 1024 + dstOff))[off] = o;
}

// ---------------- GEMM 256x256 tile, 8-phase, counted vmcnt ----------------
// C[M,N] = A[M,K] @ B[N,K]^T, K=N=1024. 512 threads = 8 waves (2Mx4N).
// Wave panels interleaved: rows = mh*128 + wr*64 + m4*16, cols = nh*128 + wc*32 + n2*16
// so phase quadrant (mh,nh) consumes exactly LDS half A[mh], B[nh] -> half-granular
// prefetch with 2 buffers is race-free.
// LDS: 2 bufs x (A 32KB + B 32KB) = 128 KiB. Swizzle: byte ^= ((b>>9)&1)<<5 ^ ((b>>10)&1)<<6
// (involution; applied to stage SOURCE and ds_read, LDS dest stays linear).
// OUTF: 0 = f16 store, 1 = f16*scale, 2 = f32 + bias
template<int OUTF>
__global__ __launch_bounds__(512, 2)
void gemm256(const f16* __restrict__ A, const f16* __restrict__ Bw,
             void* __restrict__ Cv, const float* __restrict__ bias,
             int M, long sA, long sB, long sC, float scale)
{
  constexpr int K = 1024, N = 1024, T = K / 64;
  __shared__ __align__(16) char lds[131072];
  const int bz = blockIdx.z;
  const f16* Ab = A + (long)bz * sA;
  const f16* Bb = Bw + (long)bz * sB;
  const int t = threadIdx.x;
  const int w = t >> 6, l = t & 63;
  const int wr = w >> 2, wc = w & 3;
  const int brow = blockIdx.y * 256, bcol = blockIdx.x * 256;

  f32x4 acc[2][4][2][2] = {};  // [mh][m4][nh][n2]

  // staging: thread t covers row (t>>3) of a 64-row group, 16B at swizzled col
  const int srow = t >> 3;
  const int scol = ((t & 7) * 8) ^ (((t >> 5) & 1) << 4) ^ (((t >> 6) & 1) << 5);
  // frag-read swizzle mask (row bits 2,3 -> byte bits 5,6)
  const int xmask = (((l >> 2) & 1) << 5) | (((l >> 3) & 1) << 6);
  const int lrow = l & 15, lslot = (l >> 4) * 16;

  auto stageA = [&](int kt, int h) {
    char* dst = lds + (kt & 1) * 65536 + h * 16384;
    #pragma unroll
    for (int j = 0; j < 2; ++j) {
      int ar = brow + h * 128 + j * 64 + srow;
      if (ar >= M) ar = M - 1;
      const f16* g = Ab + (long)ar * K + kt * 64 + scol;
      __builtin_amdgcn_global_load_lds(AS1(g), AS3(dst + j * 8192 + t * 16), 16, 0, 0);
    }
  };
  auto stageB = [&](int kt, int h) {
    char* dst = lds + (kt & 1) * 65536 + 32768 + h * 16384;
    #pragma unroll
    for (int j = 0; j < 2; ++j) {
      int br = bcol + h * 128 + j * 64 + srow;  // N always full
      const f16* g = Bb + (long)br * K + kt * 64 + scol;
      __builtin_amdgcn_global_load_lds(AS1(g), AS3(dst + j * 8192 + t * 16), 16, 0, 0);
    }
  };
  auto ldA = [&](int kt, int mh, f16x8* a) {
    const char* base = lds + (kt & 1) * 65536;
    #pragma unroll
    for (int m4 = 0; m4 < 4; ++m4)
      #pragma unroll
      for (int kk = 0; kk < 2; ++kk) {
        int rowA = mh * 128 + wr * 64 + m4 * 16 + lrow;
        int off = (rowA * 128 + kk * 64 + lslot) ^ xmask;
        a[m4 * 2 + kk] = *(const f16x8*)(base + off);
      }
  };
  auto ldB = [&](int kt, int nh, f16x8* b) {
    const char* base = lds + (kt & 1) * 65536 + 32768;
    #pragma unroll
    for (int n2 = 0; n2 < 2; ++n2)
      #pragma unroll
      for (int kk = 0; kk < 2; ++kk) {
        int rowB = nh * 128 + wc * 32 + n2 * 16 + lrow;
        int off = (rowB * 128 + kk * 64 + lslot) ^ xmask;
        b[n2 * 2 + kk] = *(const f16x8*)(base + off);
      }
  };
  auto mma = [&](int mh, int nh, const f16x8* a, const f16x8* b) {
    __builtin_amdgcn_s_setprio(1);
    #pragma unroll
    for (int m4 = 0; m4 < 4; ++m4)
      #pragma unroll
      for (int n2 = 0; n2 < 2; ++n2)
        #pragma unroll
        for (int kk = 0; kk < 2; ++kk)
          acc[mh][m4][nh][n2] = __builtin_amdgcn_mfma_f32_16x16x32_f16(
              a[m4 * 2 + kk], b[n2 * 2 + kk], acc[mh][m4][nh][n2], 0, 0, 0);
    __builtin_amdgcn_s_setprio(0);
  };

  // prologue: tile0 fully + A0,B1 of tile1 (6 halves, 12 loads)
  stageA(0, 0); stageA(0, 1); stageB(0, 0); stageB(0, 1);
  stageA(1, 0); stageB(1, 1);
  VMCNT(4);            // tile0's 8 loads landed; A0(1),B1(1) in flight
  BAR();

  f16x8 a[8], b0[4], b1[4];
  for (int kt = 0; kt < T; ++kt) {
    // phase 1: quadrant (0,0) — consumes A-half0 + B-half0
    ldA(kt, 0, a); ldB(kt, 0, b0);
    if (kt + 1 < T) stageA(kt + 1, 1);
    BAR();
    mma(0, 0, a, b0);
    BAR();
    // phase 2: (0,1) — A-half0 (last use) + B-half1
    ldB(kt, 1, b1);
    if (kt + 1 < T) stageB(kt + 1, 0);
    BAR();
    mma(0, 1, a, b1);
    BAR();
    // phase 3: (1,1) — A-half1 + B-half1 (last use); A-half0 of this buf now free
    ldA(kt, 1, a);
    if (kt + 2 < T) stageA(kt + 2, 0);
    BAR();
    mma(1, 1, a, b1);
    BAR();
    // phase 4: (1,0) — no ds_read (a from ph3, b0 from ph1); B-half1 free
    if (kt + 2 < T) {
      stageB(kt + 2, 1);
      VMCNT(4);        // tile kt+1 fully landed; 2 halves of kt+2 stay in flight
    } else if (kt + 1 < T) {
      VMCNT(0);        // final drain: tile kt+1 complete
    }
    BAR();
    mma(1, 0, a, b0);
    BAR();
  }

  // epilogue: C/D layout col = lane&15, row = (lane>>4)*4 + reg
  const int rj = (l >> 4) * 4;
  #pragma unroll
  for (int mh = 0; mh < 2; ++mh)
    #pragma unroll
    for (int m4 = 0; m4 < 4; ++m4)
      #pragma unroll
      for (int j = 0; j < 4; ++j) {
        const int r = brow + mh * 128 + wr * 64 + m4 * 16 + rj + j;
        if (r >= M) continue;
        #pragma unroll
        for (int nh = 0; nh < 2; ++nh)
          #pragma unroll
          for (int n2 = 0; n2 < 2; ++n2) {
            const int c = bcol + nh * 128 + wc * 32 + n2 * 16 + lrow;
            float v = acc[mh][m4][nh][n2][j];
            if constexpr (OUTF == 0) {
              ((f16*)Cv)[(long)bz * sC + (long)r * N + c] = (f16)v;
            } else if constexpr (OUTF == 1) {
              ((f16*)Cv)[(long)bz * sC + (long)r * N + c] = (f16)(v * scale);
            } else {
              ((float*)Cv)[(long)bz * sC + (long)r * N + c] = v + bias[c];
            }
          }
      }
}

// ---------------- row softmax, in-place on fp16 [B*S, 1024] ----------------
__global__ __launch_bounds__(256)
void softmax_rows(f16* __restrict__ S) {
  const long row = blockIdx.x;
  f16* p = S + row * 1024;
  const int t = threadIdx.x;
  f16x4 v4 = ((f16x4*)p)[t];
  float v[4];
  #pragma unroll
  for (int j = 0; j < 4; ++j) v[j] = (float)v4[j];

  float m = fmaxf(fmaxf(v[0], v[1]), fmaxf(v[2], v[3]));
  #pragma unroll
  for (int off = 1; off < 64; off <<= 1) m = fmaxf(m, __shfl_xor(m, off));
  __shared__ float sm[4], ss[4];
  const int w = t >> 6;
  if ((t & 63) == 0) sm[w] = m;
  __syncthreads();
  m = fmaxf(fmaxf(sm[0], sm[1]), fmaxf(sm[2], sm[3]));

  float e[4], s = 0.f;
  #pragma unroll
  for (int j = 0; j < 4; ++j) { e[j] = __expf(v[j] - m); s += e[j]; }
  #pragma unroll
  for (int off = 1; off < 64; off <<= 1) s += __shfl_xor(s, off);
  if ((t & 63) == 0) ss[w] = s;
  __syncthreads();
  s = ss[0] + ss[1] + ss[2] + ss[3];
  const float inv = 1.f / s;

  f16x4 o;
  #pragma unroll
  for (int j = 0; j < 4; ++j) o[j] = (f16)(e[j] * inv);
  ((f16x4*)p)[t] = o;
}

// ---------------- per-batch 1024x1024 fp16 transpose ----------------
__global__ void transpose_f16(const f16* __restrict__ in, f16* __restrict__ out) {
  __shared__ f16 tile[32][33];
  const long bs = (long)blockIdx.z * 1024 * 1024;
  const int r0 = blockIdx.y * 32, c0 = blockIdx.x * 32;
  const int tx = threadIdx.x, ty = threadIdx.y;
  #pragma unroll
  for (int i = 0; i < 4; ++i)
    tile[ty + 8 * i][tx] = in[bs + (long)(r0 + ty + 8 * i) * 1024 + c0 + tx];
  __syncthreads();
  #pragma unroll
  for (int i = 0; i < 4; ++i)
    out[bs + (long)(c0 + ty + 8 * i) * 1024 + r0 + tx] = tile[tx][ty + 8 * i];
}

// ---------------- launch ----------------
extern "C" void kernel_launch(void* const* d_in, const int* in_sizes, int n_in,
                              void* d_out, int out_size, void* d_ws, size_t ws_size,
                              hipStream_t stream) {
  const float* vis = (const float*)d_in[0];
  const float* lan = (const float*)d_in[1];
  const float* Wv  = (const float*)d_in[2];
  const float* Wl  = (const float*)d_in[3];
  const float* Wo  = (const float*)d_in[4];
  const float* bo  = (const float*)d_in[5];
  float* out = (float*)d_out;

  const long PB = 1024l * 1024;
  const long SE = 16 * PB;

  f16* Ah  = (f16*)d_ws;
  f16* Xh  = Ah + SE;
  f16* Sc  = Xh + SE;
  f16* Wvh = Sc + SE;
  f16* Wlh = Wvh + PB;
  f16* Woh = Wlh + PB;
  f16* XhT = Ah;   // alias: Ah dead after projections
  f16* Att = Xh;   // alias: Xh dead after transpose+scores

  {
    long n4 = 16l * 576 * 1024 / 4;
    conv_tokens<<<dim3((n4 + 255) / 256), 256, 0, stream>>>(vis, Ah, 576, 0, n4);
  }
  {
    long n4 = 16l * 448 * 1024 / 4;
    conv_tokens<<<dim3((n4 + 255) / 256), 256, 0, stream>>>(lan, Ah, 448, 576l * 1024, n4);
  }
  {
    long n4 = PB / 4;
    conv_f32_to_f16<<<dim3((n4 + 255) / 256), 256, 0, stream>>>(Wv, Wvh, n4);
    conv_f32_to_f16<<<dim3((n4 + 255) / 256), 256, 0, stream>>>(Wl, Wlh, n4);
    conv_f32_to_f16<<<dim3((n4 + 255) / 256), 256, 0, stream>>>(Wo, Woh, n4);
  }
  // projections: X = tokens @ W^T
  gemm256<0><<<dim3(4, 3, 16), 512, 0, stream>>>(Ah, Wvh, Xh, nullptr, 576, PB, 0, PB, 1.f);
  gemm256<0><<<dim3(4, 2, 16), 512, 0, stream>>>(Ah + 576l * 1024, Wlh, Xh + 576l * 1024,
                                                 nullptr, 448, PB, 0, PB, 1.f);
  // scores = (X @ X^T) / 32
  gemm256<1><<<dim3(4, 4, 16), 512, 0, stream>>>(Xh, Xh, Sc, nullptr, 1024, PB, PB, PB,
                                                 0.03125f);
  // transpose X for the PV step
  transpose_f16<<<dim3(32, 32, 16), dim3(32, 8), 0, stream>>>(Xh, XhT);
  // softmax rows in place
  softmax_rows<<<dim3(16 * 1024), 256, 0, stream>>>(Sc);
  // attended = P @ X
  gemm256<0><<<dim3(4, 4, 16), 512, 0, stream>>>(Sc, XhT, Att, nullptr, 1024, PB, PB, PB, 1.f);
  // out = attended @ Wo^T + bo
  gemm256<2><<<dim3(4, 64, 1), 512, 0, stream>>>(Att, Woh, out, bo, 16384, 0, 0, 0, 1.f);
}

// Round 6
// 340.684 us; speedup vs baseline: 1.2088x; 1.0427x over previous
//
#include <hip/hip_runtime.h>

typedef _Float16 f16;
typedef _Float16 f16x4 __attribute__((ext_vector_type(4)));
typedef _Float16 f16x8 __attribute__((ext_vector_type(8)));
typedef float f32x4 __attribute__((ext_vector_type(4)));

#define AS1(p) ((const __attribute__((address_space(1))) void*)(p))
#define AS3(p) ((__attribute__((address_space(3))) void*)(p))
#define BAR() { asm volatile("" ::: "memory"); __builtin_amdgcn_s_barrier(); \
                asm volatile("" ::: "memory"); __builtin_amdgcn_sched_barrier(0); }
#define VMCNT(n) asm volatile("s_waitcnt vmcnt(" #n ")" ::: "memory")

// ---------------- conversion kernels ----------------

__global__ void conv_f32_to_f16(const float* __restrict__ src, f16* __restrict__ dst, long n4) {
  long i = (long)blockIdx.x * blockDim.x + threadIdx.x;
  if (i >= n4) return;
  const float4 v = ((const float4*)src)[i];
  f16x4 o = { (f16)v.x, (f16)v.y, (f16)v.z, (f16)v.w };
  ((f16x4*)dst)[i] = o;
}

__global__ void conv_tokens(const float* __restrict__ src, f16* __restrict__ dst,
                            int rpb, long dstOff, long n4) {
  long i = (long)blockIdx.x * blockDim.x + threadIdx.x;
  if (i >= n4) return;
  long perB = (long)rpb * 256;
  long b = i / perB, off = i % perB;
  const float4 v = ((const float4*)src)[i];
  f16x4 o = { (f16)v.x, (f16)v.y, (f16)v.z, (f16)v.w };
  ((f16x4*)(dst + b * 1024 * 1024 + dstOff))[off] = o;
}

// ---------------- GEMM 256x256 tile, 8-phase, counted vmcnt ----------------
// C[M,N] = A[M,K] @ B[N,K]^T, K=N=1024. 512 threads = 8 waves (2Mx4N).
// XCD-affine 1-D grid remap: blocks sharing operand panels get ids == (mod 8)
// so they co-reside on one XCD's L2 (dispatch model: xcd = id%8).
//   group g = (by/CHY) + NBYC*bz; within-group w = bx + GX*(by%CHY); CPG = GX*CHY.
//   id = (g%8) + 8*(w + CPG*(g/8)).  Requires NGRP % 8 == 0 (verified per launch).
// LDS swizzle (G4): byte ^= (row&7)<<4 — 16-lane read groups spread over all 8
// 16B slots, 2 lanes/bank = conflict-free. Applied to stage SOURCE (global col)
// and ds_read addr; LDS dest stays linear (global_load_lds constraint).
// OUTF: 0 = f16 store, 1 = f16*scale, 2 = f32 + bias
template<int OUTF>
__global__ __launch_bounds__(512, 2)
void gemm256(const f16* __restrict__ A, const f16* __restrict__ Bw,
             void* __restrict__ Cv, const float* __restrict__ bias,
             int M, long sA, long sB, long sC, float scale,
             int GX, int CHY, int NBYC, int CPG)
{
  constexpr int K = 1024, N = 1024, T = K / 64;
  __shared__ __align__(16) char lds[131072];

  // ---- XCD-affine decode ----
  const int id = blockIdx.x;
  const int xcd = id & 7, q = id >> 3;
  const int wi = q % CPG, ghi = q / CPG;
  const int g = xcd + 8 * ghi;
  const int bchunk = g % NBYC, bz = g / NBYC;
  const int bx = wi % GX, by = bchunk * CHY + wi / GX;

  const f16* Ab = A + (long)bz * sA;
  const f16* Bb = Bw + (long)bz * sB;
  const int t = threadIdx.x;
  const int w = t >> 6, l = t & 63;
  const int wr = w >> 2, wc = w & 3;
  const int brow = by * 256, bcol = bx * 256;

  f32x4 acc[2][4][2][2] = {};  // [mh][m4][nh][n2]

  // staging: thread t covers row (t>>3) of a 64-row group; source col swizzled
  // to match read-side (row&7)<<4 byte-XOR (row bits 0-2 = t bits 3-5).
  const int srow = t >> 3;
  const int scol = ((t & 7) * 8) ^ (((t >> 3) & 7) << 3);   // f16 elements
  // frag-read swizzle: row bits 0-2 = l bits 0-2
  const int xm = (l & 7) << 4;
  const int lrow = l & 15, lslot = (l >> 4) * 16;

  auto stageA = [&](int kt, int h) {
    char* dst = lds + (kt & 1) * 65536 + h * 16384;
    #pragma unroll
    for (int j = 0; j < 2; ++j) {
      int ar = brow + h * 128 + j * 64 + srow;
      if (ar >= M) ar = M - 1;
      const f16* gp = Ab + (long)ar * K + kt * 64 + scol;
      __builtin_amdgcn_global_load_lds(AS1(gp), AS3(dst + j * 8192 + t * 16), 16, 0, 0);
    }
  };
  auto stageB = [&](int kt, int h) {
    char* dst = lds + (kt & 1) * 65536 + 32768 + h * 16384;
    #pragma unroll
    for (int j = 0; j < 2; ++j) {
      int br = bcol + h * 128 + j * 64 + srow;  // N always full
      const f16* gp = Bb + (long)br * K + kt * 64 + scol;
      __builtin_amdgcn_global_load_lds(AS1(gp), AS3(dst + j * 8192 + t * 16), 16, 0, 0);
    }
  };
  auto ldA = [&](int kt, int mh, f16x8* a) {
    const char* base = lds + (kt & 1) * 65536;
    #pragma unroll
    for (int m4 = 0; m4 < 4; ++m4)
      #pragma unroll
      for (int kk = 0; kk < 2; ++kk) {
        int rowA = mh * 128 + wr * 64 + m4 * 16 + lrow;
        int off = (rowA * 128 + kk * 64 + lslot) ^ xm;
        a[m4 * 2 + kk] = *(const f16x8*)(base + off);
      }
  };
  auto ldB = [&](int kt, int nh, f16x8* b) {
    const char* base = lds + (kt & 1) * 65536 + 32768;
    #pragma unroll
    for (int n2 = 0; n2 < 2; ++n2)
      #pragma unroll
      for (int kk = 0; kk < 2; ++kk) {
        int rowB = nh * 128 + wc * 32 + n2 * 16 + lrow;
        int off = (rowB * 128 + kk * 64 + lslot) ^ xm;
        b[n2 * 2 + kk] = *(const f16x8*)(base + off);
      }
  };
  auto mma = [&](int mh, int nh, const f16x8* a, const f16x8* b) {
    __builtin_amdgcn_s_setprio(1);
    #pragma unroll
    for (int m4 = 0; m4 < 4; ++m4)
      #pragma unroll
      for (int n2 = 0; n2 < 2; ++n2)
        #pragma unroll
        for (int kk = 0; kk < 2; ++kk)
          acc[mh][m4][nh][n2] = __builtin_amdgcn_mfma_f32_16x16x32_f16(
              a[m4 * 2 + kk], b[n2 * 2 + kk], acc[mh][m4][nh][n2], 0, 0, 0);
    __builtin_amdgcn_s_setprio(0);
  };

  // prologue: tile0 fully + A0,B1 of tile1
  stageA(0, 0); stageA(0, 1); stageB(0, 0); stageB(0, 1);
  stageA(1, 0); stageB(1, 1);
  VMCNT(4);
  BAR();

  f16x8 a[8], b0[4], b1[4];
  for (int kt = 0; kt < T; ++kt) {
    // phase 1: quadrant (0,0)
    ldA(kt, 0, a); ldB(kt, 0, b0);
    if (kt + 1 < T) stageA(kt + 1, 1);
    BAR();
    mma(0, 0, a, b0);
    BAR();
    // phase 2: (0,1)
    ldB(kt, 1, b1);
    if (kt + 1 < T) stageB(kt + 1, 0);
    BAR();
    mma(0, 1, a, b1);
    BAR();
    // phase 3: (1,1)
    ldA(kt, 1, a);
    if (kt + 2 < T) stageA(kt + 2, 0);
    BAR();
    mma(1, 1, a, b1);
    BAR();
    // phase 4: (1,0)
    if (kt + 2 < T) {
      stageB(kt + 2, 1);
      VMCNT(4);        // tile kt+1 fully landed; kt+2 halves stay in flight
    } else if (kt + 1 < T) {
      VMCNT(0);        // final drain
    }
    BAR();
    mma(1, 0, a, b0);
    BAR();
  }

  // epilogue: C/D layout col = lane&15, row = (lane>>4)*4 + reg
  const int rj = (l >> 4) * 4;
  #pragma unroll
  for (int mh = 0; mh < 2; ++mh)
    #pragma unroll
    for (int m4 = 0; m4 < 4; ++m4)
      #pragma unroll
      for (int j = 0; j < 4; ++j) {
        const int r = brow + mh * 128 + wr * 64 + m4 * 16 + rj + j;
        if (r >= M) continue;
        #pragma unroll
        for (int nh = 0; nh < 2; ++nh)
          #pragma unroll
          for (int n2 = 0; n2 < 2; ++n2) {
            const int c = bcol + nh * 128 + wc * 32 + n2 * 16 + lrow;
            float v = acc[mh][m4][nh][n2][j];
            if constexpr (OUTF == 0) {
              ((f16*)Cv)[(long)bz * sC + (long)r * N + c] = (f16)v;
            } else if constexpr (OUTF == 1) {
              ((f16*)Cv)[(long)bz * sC + (long)r * N + c] = (f16)(v * scale);
            } else {
              ((float*)Cv)[(long)bz * sC + (long)r * N + c] = v + bias[c];
            }
          }
      }
}

// ---------------- row softmax, in-place on fp16 [B*S, 1024] ----------------
__global__ __launch_bounds__(256)
void softmax_rows(f16* __restrict__ S) {
  const long row = blockIdx.x;
  f16* p = S + row * 1024;
  const int t = threadIdx.x;
  f16x4 v4 = ((f16x4*)p)[t];
  float v[4];
  #pragma unroll
  for (int j = 0; j < 4; ++j) v[j] = (float)v4[j];

  float m = fmaxf(fmaxf(v[0], v[1]), fmaxf(v[2], v[3]));
  #pragma unroll
  for (int off = 1; off < 64; off <<= 1) m = fmaxf(m, __shfl_xor(m, off));
  __shared__ float sm[4], ss[4];
  const int w = t >> 6;
  if ((t & 63) == 0) sm[w] = m;
  __syncthreads();
  m = fmaxf(fmaxf(sm[0], sm[1]), fmaxf(sm[2], sm[3]));

  float e[4], s = 0.f;
  #pragma unroll
  for (int j = 0; j < 4; ++j) { e[j] = __expf(v[j] - m); s += e[j]; }
  #pragma unroll
  for (int off = 1; off < 64; off <<= 1) s += __shfl_xor(s, off);
  if ((t & 63) == 0) ss[w] = s;
  __syncthreads();
  s = ss[0] + ss[1] + ss[2] + ss[3];
  const float inv = 1.f / s;

  f16x4 o;
  #pragma unroll
  for (int j = 0; j < 4; ++j) o[j] = (f16)(e[j] * inv);
  ((f16x4*)p)[t] = o;
}

// ---------------- per-batch 1024x1024 fp16 transpose ----------------
__global__ void transpose_f16(const f16* __restrict__ in, f16* __restrict__ out) {
  __shared__ f16 tile[32][33];
  const long bs = (long)blockIdx.z * 1024 * 1024;
  const int r0 = blockIdx.y * 32, c0 = blockIdx.x * 32;
  const int tx = threadIdx.x, ty = threadIdx.y;
  #pragma unroll
  for (int i = 0; i < 4; ++i)
    tile[ty + 8 * i][tx] = in[bs + (long)(r0 + ty + 8 * i) * 1024 + c0 + tx];
  __syncthreads();
  #pragma unroll
  for (int i = 0; i < 4; ++i)
    out[bs + (long)(c0 + ty + 8 * i) * 1024 + r0 + tx] = tile[tx][ty + 8 * i];
}

// ---------------- launch ----------------
extern "C" void kernel_launch(void* const* d_in, const int* in_sizes, int n_in,
                              void* d_out, int out_size, void* d_ws, size_t ws_size,
                              hipStream_t stream) {
  const float* vis = (const float*)d_in[0];
  const float* lan = (const float*)d_in[1];
  const float* Wv  = (const float*)d_in[2];
  const float* Wl  = (const float*)d_in[3];
  const float* Wo  = (const float*)d_in[4];
  const float* bo  = (const float*)d_in[5];
  float* out = (float*)d_out;

  const long PB = 1024l * 1024;
  const long SE = 16 * PB;

  f16* Ah  = (f16*)d_ws;
  f16* Xh  = Ah + SE;
  f16* Sc  = Xh + SE;
  f16* Wvh = Sc + SE;
  f16* Wlh = Wvh + PB;
  f16* Woh = Wlh + PB;
  f16* XhT = Ah;   // alias: Ah dead after projections
  f16* Att = Xh;   // alias: Xh dead after transpose+scores

  {
    long n4 = 16l * 576 * 1024 / 4;
    conv_tokens<<<dim3((n4 + 255) / 256), 256, 0, stream>>>(vis, Ah, 576, 0, n4);
  }
  {
    long n4 = 16l * 448 * 1024 / 4;
    conv_tokens<<<dim3((n4 + 255) / 256), 256, 0, stream>>>(lan, Ah, 448, 576l * 1024, n4);
  }
  {
    long n4 = PB / 4;
    conv_f32_to_f16<<<dim3((n4 + 255) / 256), 256, 0, stream>>>(Wv, Wvh, n4);
    conv_f32_to_f16<<<dim3((n4 + 255) / 256), 256, 0, stream>>>(Wl, Wlh, n4);
    conv_f32_to_f16<<<dim3((n4 + 255) / 256), 256, 0, stream>>>(Wo, Woh, n4);
  }
  // projections: X = tokens @ W^T  (GX,CHY,NBYC,CPG): NGRP = NBYC*NZ % 8 == 0
  gemm256<0><<<dim3(192), 512, 0, stream>>>(Ah, Wvh, Xh, nullptr, 576, PB, 0, PB, 1.f,
                                            4, 1, 3, 4);    // NGRP=48
  gemm256<0><<<dim3(128), 512, 0, stream>>>(Ah + 576l * 1024, Wlh, Xh + 576l * 1024,
                                            nullptr, 448, PB, 0, PB, 1.f,
                                            4, 1, 2, 4);    // NGRP=32
  // scores = (X @ X^T) / 32 — whole batch on one XCD (NGRP=16)
  gemm256<1><<<dim3(256), 512, 0, stream>>>(Xh, Xh, Sc, nullptr, 1024, PB, PB, PB,
                                            0.03125f, 4, 4, 1, 16);
  // transpose X for the PV step
  transpose_f16<<<dim3(32, 32, 16), dim3(32, 8), 0, stream>>>(Xh, XhT);
  // softmax rows in place
  softmax_rows<<<dim3(16 * 1024), 256, 0, stream>>>(Sc);
  // attended = P @ X — batch-affine (NGRP=16)
  gemm256<0><<<dim3(256), 512, 0, stream>>>(Sc, XhT, Att, nullptr, 1024, PB, PB, PB, 1.f,
                                            4, 4, 1, 16);
  // out = attended @ Wo^T + bo — 8 brow-panels per XCD (NGRP=8)
  gemm256<2><<<dim3(256), 512, 0, stream>>>(Att, Woh, out, bo, 16384, 0, 0, 0, 1.f,
                                            4, 8, 8, 32);
}

// Round 8
// 325.963 us; speedup vs baseline: 1.2634x; 1.0452x over previous
//
#include <hip/hip_runtime.h>

typedef _Float16 f16;
typedef _Float16 f16x4 __attribute__((ext_vector_type(4)));
typedef _Float16 f16x8 __attribute__((ext_vector_type(8)));
typedef float f32x4 __attribute__((ext_vector_type(4)));

#define AS1(p) ((const __attribute__((address_space(1))) void*)(p))
#define AS3(p) ((__attribute__((address_space(3))) void*)(p))
#define BAR() { asm volatile("" ::: "memory"); __builtin_amdgcn_s_barrier(); \
                asm volatile("" ::: "memory"); __builtin_amdgcn_sched_barrier(0); }
#define VMCNT(n) asm volatile("s_waitcnt vmcnt(" #n ")" ::: "memory")

// ---------------- fused conversion kernel ----------------
// Converts all fp32 inputs to fp16 in one launch (saves 4 kernel-launch gaps).
// Regions (in float4 units): vision tokens | language tokens | Wv | Wl | Wo.
__global__ void conv_all(const float* __restrict__ vis, const float* __restrict__ lan,
                         const float* __restrict__ Wv, const float* __restrict__ Wl,
                         const float* __restrict__ Wo,
                         f16* __restrict__ Ah, f16* __restrict__ Wh,
                         long nV4, long nL4, long nW4) {
  const long i = (long)blockIdx.x * blockDim.x + threadIdx.x;
  const float* src;
  f16* dst;
  long soff, doff;
  if (i < nV4) {
    const long perB = 576l * 256;
    long b = i / perB, off = i % perB;
    src = vis; soff = i;
    dst = Ah + b * 1048576; doff = off;
  } else if (i < nV4 + nL4) {
    long j = i - nV4;
    const long perB = 448l * 256;
    long b = j / perB, off = j % perB;
    src = lan; soff = j;
    dst = Ah + b * 1048576 + 576l * 1024; doff = off;
  } else {
    long j = i - nV4 - nL4;
    if (j >= 3 * nW4) return;
    long which = j / nW4, off = j % nW4;
    src = which == 0 ? Wv : (which == 1 ? Wl : Wo);
    soff = off;
    dst = Wh + which * 1048576; doff = off;
  }
  const float4 v = ((const float4*)src)[soff];
  f16x4 o = { (f16)v.x, (f16)v.y, (f16)v.z, (f16)v.w };
  ((f16x4*)dst)[doff] = o;
}

// ---------------- GEMM 256x256 tile, 8-phase, counted vmcnt ----------------
// C[M,N] = A[M,K] @ B[N,K]^T, K=N=1024. 512 threads = 8 waves (2Mx4N).
// XCD-affine 1-D grid remap: blocks sharing operand panels get ids == (mod 8)
// so they co-reside on one XCD's L2 (dispatch model: xcd = id%8).
//   group g = (by/CHY) + NBYC*bz; within-group w = bx + GX*(by%CHY); CPG = GX*CHY.
//   id = (g%8) + 8*(w + CPG*(g/8)).  Requires NGRP % 8 == 0 (verified per launch).
// LDS swizzle (G4): byte ^= (row&7)<<4 — verified r6: SQ_LDS_BANK_CONFLICT = 0.
// OUTF: 0 = f16 store, 1 = f16*scale, 2 = f32 + bias
template<int OUTF>
__global__ __launch_bounds__(512, 2)
void gemm256(const f16* __restrict__ A, const f16* __restrict__ Bw,
             void* __restrict__ Cv, const float* __restrict__ bias,
             int M, long sA, long sB, long sC, float scale,
             int GX, int CHY, int NBYC, int CPG)
{
  constexpr int K = 1024, N = 1024, T = K / 64;
  __shared__ __align__(16) char lds[131072];

  // ---- XCD-affine decode ----
  const int id = blockIdx.x;
  const int xcd = id & 7, q = id >> 3;
  const int wi = q % CPG, ghi = q / CPG;
  const int g = xcd + 8 * ghi;
  const int bchunk = g % NBYC, bz = g / NBYC;
  const int bx = wi % GX, by = bchunk * CHY + wi / GX;

  const f16* Ab = A + (long)bz * sA;
  const f16* Bb = Bw + (long)bz * sB;
  const int t = threadIdx.x;
  const int w = t >> 6, l = t & 63;
  const int wr = w >> 2, wc = w & 3;
  const int brow = by * 256, bcol = bx * 256;

  f32x4 acc[2][4][2][2] = {};  // [mh][m4][nh][n2]

  const int srow = t >> 3;
  const int scol = ((t & 7) * 8) ^ (((t >> 3) & 7) << 3);   // f16 elements
  const int xm = (l & 7) << 4;
  const int lrow = l & 15, lslot = (l >> 4) * 16;

  auto stageA = [&](int kt, int h) {
    char* dst = lds + (kt & 1) * 65536 + h * 16384;
    #pragma unroll
    for (int j = 0; j < 2; ++j) {
      int ar = brow + h * 128 + j * 64 + srow;
      if (ar >= M) ar = M - 1;
      const f16* gp = Ab + (long)ar * K + kt * 64 + scol;
      __builtin_amdgcn_global_load_lds(AS1(gp), AS3(dst + j * 8192 + t * 16), 16, 0, 0);
    }
  };
  auto stageB = [&](int kt, int h) {
    char* dst = lds + (kt & 1) * 65536 + 32768 + h * 16384;
    #pragma unroll
    for (int j = 0; j < 2; ++j) {
      int br = bcol + h * 128 + j * 64 + srow;
      const f16* gp = Bb + (long)br * K + kt * 64 + scol;
      __builtin_amdgcn_global_load_lds(AS1(gp), AS3(dst + j * 8192 + t * 16), 16, 0, 0);
    }
  };
  auto ldA = [&](int kt, int mh, f16x8* a) {
    const char* base = lds + (kt & 1) * 65536;
    #pragma unroll
    for (int m4 = 0; m4 < 4; ++m4)
      #pragma unroll
      for (int kk = 0; kk < 2; ++kk) {
        int rowA = mh * 128 + wr * 64 + m4 * 16 + lrow;
        int off = (rowA * 128 + kk * 64 + lslot) ^ xm;
        a[m4 * 2 + kk] = *(const f16x8*)(base + off);
      }
  };
  auto ldB = [&](int kt, int nh, f16x8* b) {
    const char* base = lds + (kt & 1) * 65536 + 32768;
    #pragma unroll
    for (int n2 = 0; n2 < 2; ++n2)
      #pragma unroll
      for (int kk = 0; kk < 2; ++kk) {
        int rowB = nh * 128 + wc * 32 + n2 * 16 + lrow;
        int off = (rowB * 128 + kk * 64 + lslot) ^ xm;
        b[n2 * 2 + kk] = *(const f16x8*)(base + off);
      }
  };
  auto mma = [&](int mh, int nh, const f16x8* a, const f16x8* b) {
    __builtin_amdgcn_s_setprio(1);
    #pragma unroll
    for (int m4 = 0; m4 < 4; ++m4)
      #pragma unroll
      for (int n2 = 0; n2 < 2; ++n2)
        #pragma unroll
        for (int kk = 0; kk < 2; ++kk)
          acc[mh][m4][nh][n2] = __builtin_amdgcn_mfma_f32_16x16x32_f16(
              a[m4 * 2 + kk], b[n2 * 2 + kk], acc[mh][m4][nh][n2], 0, 0, 0);
    __builtin_amdgcn_s_setprio(0);
  };

  // prologue: tile0 fully + A0,B1 of tile1
  stageA(0, 0); stageA(0, 1); stageB(0, 0); stageB(0, 1);
  stageA(1, 0); stageB(1, 1);
  VMCNT(4);
  BAR();

  f16x8 a[8], b0[4], b1[4];
  for (int kt = 0; kt < T; ++kt) {
    // phase 1: quadrant (0,0)
    ldA(kt, 0, a); ldB(kt, 0, b0);
    if (kt + 1 < T) stageA(kt + 1, 1);
    BAR();
    mma(0, 0, a, b0);
    BAR();
    // phase 2: (0,1)
    ldB(kt, 1, b1);
    if (kt + 1 < T) stageB(kt + 1, 0);
    BAR();
    mma(0, 1, a, b1);
    BAR();
    // phase 3: (1,1)
    ldA(kt, 1, a);
    if (kt + 2 < T) stageA(kt + 2, 0);
    BAR();
    mma(1, 1, a, b1);
    BAR();
    // phase 4: (1,0)
    if (kt + 2 < T) {
      stageB(kt + 2, 1);
      VMCNT(4);        // tile kt+1 fully landed; kt+2 halves stay in flight
    } else if (kt + 1 < T) {
      VMCNT(0);        // final drain
    }
    BAR();
    mma(1, 0, a, b0);
    BAR();
  }

  // epilogue: C/D layout col = lane&15, row = (lane>>4)*4 + reg
  const int rj = (l >> 4) * 4;
  #pragma unroll
  for (int mh = 0; mh < 2; ++mh)
    #pragma unroll
    for (int m4 = 0; m4 < 4; ++m4)
      #pragma unroll
      for (int j = 0; j < 4; ++j) {
        const int r = brow + mh * 128 + wr * 64 + m4 * 16 + rj + j;
        if (r >= M) continue;
        #pragma unroll
        for (int nh = 0; nh < 2; ++nh)
          #pragma unroll
          for (int n2 = 0; n2 < 2; ++n2) {
            const int c = bcol + nh * 128 + wc * 32 + n2 * 16 + lrow;
            float v = acc[mh][m4][nh][n2][j];
            if constexpr (OUTF == 0) {
              ((f16*)Cv)[(long)bz * sC + (long)r * N + c] = (f16)v;
            } else if constexpr (OUTF == 1) {
              ((f16*)Cv)[(long)bz * sC + (long)r * N + c] = (f16)(v * scale);
            } else {
              ((float*)Cv)[(long)bz * sC + (long)r * N + c] = v + bias[c];
            }
          }
      }
}

// ---------------- row softmax, in-place on fp16 [B*S, 1024] ----------------
__global__ __launch_bounds__(256)
void softmax_rows(f16* __restrict__ S) {
  const long row = blockIdx.x;
  f16* p = S + row * 1024;
  const int t = threadIdx.x;
  f16x4 v4 = ((f16x4*)p)[t];
  float v[4];
  #pragma unroll
  for (int j = 0; j < 4; ++j) v[j] = (float)v4[j];

  float m = fmaxf(fmaxf(v[0], v[1]), fmaxf(v[2], v[3]));
  #pragma unroll
  for (int off = 1; off < 64; off <<= 1) m = fmaxf(m, __shfl_xor(m, off));
  __shared__ float sm[4], ss[4];
  const int w = t >> 6;
  if ((t & 63) == 0) sm[w] = m;
  __syncthreads();
  m = fmaxf(fmaxf(sm[0], sm[1]), fmaxf(sm[2], sm[3]));

  float e[4], s = 0.f;
  #pragma unroll
  for (int j = 0; j < 4; ++j) { e[j] = __expf(v[j] - m); s += e[j]; }
  #pragma unroll
  for (int off = 1; off < 64; off <<= 1) s += __shfl_xor(s, off);
  if ((t & 63) == 0) ss[w] = s;
  __syncthreads();
  s = ss[0] + ss[1] + ss[2] + ss[3];
  const float inv = 1.f / s;

  f16x4 o;
  #pragma unroll
  for (int j = 0; j < 4; ++j) o[j] = (f16)(e[j] * inv);
  ((f16x4*)p)[t] = o;
}

// ---------------- per-batch 1024x1024 fp16 transpose ----------------
// 64x64 tile, block (64,8): 64 lanes x 2B = 128B fully-coalesced wave
// accesses both directions. LDS [64][65]: adjacent-lane pairs alias one
// bank at worst (2-way = free, m136).
__global__ __launch_bounds__(512)
void transpose_f16(const f16* __restrict__ in, f16* __restrict__ out) {
  __shared__ f16 tile[64][65];
  const long bs = (long)blockIdx.z * 1024 * 1024;
  const int r0 = blockIdx.y * 64, c0 = blockIdx.x * 64;
  const int tx = threadIdx.x, ty = threadIdx.y;  // (64, 8)
  #pragma unroll
  for (int i = 0; i < 8; ++i)
    tile[ty + 8 * i][tx] = in[bs + (long)(r0 + ty + 8 * i) * 1024 + c0 + tx];
  __syncthreads();
  #pragma unroll
  for (int i = 0; i < 8; ++i)
    out[bs + (long)(c0 + ty + 8 * i) * 1024 + r0 + tx] = tile[tx][ty + 8 * i];
}

// ---------------- launch ----------------
extern "C" void kernel_launch(void* const* d_in, const int* in_sizes, int n_in,
                              void* d_out, int out_size, void* d_ws, size_t ws_size,
                              hipStream_t stream) {
  const float* vis = (const float*)d_in[0];
  const float* lan = (const float*)d_in[1];
  const float* Wv  = (const float*)d_in[2];
  const float* Wl  = (const float*)d_in[3];
  const float* Wo  = (const float*)d_in[4];
  const float* bo  = (const float*)d_in[5];
  float* out = (float*)d_out;

  const long PB = 1024l * 1024;
  const long SE = 16 * PB;

  f16* Ah  = (f16*)d_ws;
  f16* Xh  = Ah + SE;
  f16* Sc  = Xh + SE;
  f16* Wvh = Sc + SE;
  f16* Wlh = Wvh + PB;
  f16* Woh = Wlh + PB;
  f16* XhT = Ah;   // alias: Ah dead after projections
  f16* Att = Xh;   // alias: Xh dead after transpose+scores

  // 1) fused fp32->fp16 conversion of all inputs (one launch)
  {
    const long nV4 = 16l * 576 * 1024 / 4;   // 2359296
    const long nL4 = 16l * 448 * 1024 / 4;   // 1835008
    const long nW4 = PB / 4;                 // 262144
    const long tot = nV4 + nL4 + 3 * nW4;    // 4980736
    conv_all<<<dim3((tot + 255) / 256), 256, 0, stream>>>(vis, lan, Wv, Wl, Wo,
                                                          Ah, Wvh, nV4, nL4, nW4);
  }
  // projections: X = tokens @ W^T  (GX,CHY,NBYC,CPG): NGRP % 8 == 0
  gemm256<0><<<dim3(192), 512, 0, stream>>>(Ah, Wvh, Xh, nullptr, 576, PB, 0, PB, 1.f,
                                            4, 1, 3, 4);    // NGRP=48
  gemm256<0><<<dim3(128), 512, 0, stream>>>(Ah + 576l * 1024, Wlh, Xh + 576l * 1024,
                                            nullptr, 448, PB, 0, PB, 1.f,
                                            4, 1, 2, 4);    // NGRP=32
  // scores = (X @ X^T) / 32 — whole batch on one XCD (NGRP=16)
  gemm256<1><<<dim3(256), 512, 0, stream>>>(Xh, Xh, Sc, nullptr, 1024, PB, PB, PB,
                                            0.03125f, 4, 4, 1, 16);
  // transpose X for the PV step
  transpose_f16<<<dim3(16, 16, 16), dim3(64, 8), 0, stream>>>(Xh, XhT);
  // softmax rows in place
  softmax_rows<<<dim3(16 * 1024), 256, 0, stream>>>(Sc);
  // attended = P @ X — batch-affine (NGRP=16)
  gemm256<0><<<dim3(256), 512, 0, stream>>>(Sc, XhT, Att, nullptr, 1024, PB, PB, PB, 1.f,
                                            4, 4, 1, 16);
  // out = attended @ Wo^T + bo — 8 brow-panels per XCD (NGRP=8)
  gemm256<2><<<dim3(256), 512, 0, stream>>>(Att, Woh, out, bo, 16384, 0, 0, 0, 1.f,
                                            4, 8, 8, 32);
}

// Round 9
// 318.705 us; speedup vs baseline: 1.2922x; 1.0228x over previous
//
#include <hip/hip_runtime.h>

typedef _Float16 f16;
typedef _Float16 f16x4 __attribute__((ext_vector_type(4)));
typedef _Float16 f16x8 __attribute__((ext_vector_type(8)));
typedef float f32x4 __attribute__((ext_vector_type(4)));

#define AS1(p) ((const __attribute__((address_space(1))) void*)(p))
#define AS3(p) ((__attribute__((address_space(3))) void*)(p))
#define BAR() { asm volatile("" ::: "memory"); __builtin_amdgcn_s_barrier(); \
                asm volatile("" ::: "memory"); __builtin_amdgcn_sched_barrier(0); }
#define VMCNT(n) asm volatile("s_waitcnt vmcnt(" #n ")" ::: "memory")

// ---------------- conversion kernels (division-free) ----------------

// tokens: grid (1024, 16), 256 thr. Per batch 262144 float4s: vis first 147456,
// then lan 114688. Dst is linear per batch (concat layout falls out naturally).
__global__ void conv_tokens2(const float* __restrict__ vis, const float* __restrict__ lan,
                             f16* __restrict__ Ah) {
  const int b = blockIdx.y;
  const long i = (long)blockIdx.x * 256 + threadIdx.x;  // f4 index within batch
  const float4* src4 = (i < 147456)
      ? (const float4*)vis + (long)b * 147456 + i
      : (const float4*)lan + (long)b * 114688 + (i - 147456);
  const float4 v = *src4;
  f16x4 o = { (f16)v.x, (f16)v.y, (f16)v.z, (f16)v.w };
  ((f16x4*)Ah)[(long)b * 262144 + i] = o;
}

// weights: grid 3072, 256 thr. 3 x 262144 (=2^18) float4s -> Wvh|Wlh|Woh.
__global__ void conv_w3(const float* __restrict__ Wv, const float* __restrict__ Wl,
                        const float* __restrict__ Wo, f16* __restrict__ Wh) {
  const long i = (long)blockIdx.x * 256 + threadIdx.x;
  const int which = (int)(i >> 18);
  const long off = i & 262143;
  const float* src = which == 0 ? Wv : (which == 1 ? Wl : Wo);
  const float4 v = ((const float4*)src)[off];
  f16x4 o = { (f16)v.x, (f16)v.y, (f16)v.z, (f16)v.w };
  ((f16x4*)Wh)[i] = o;
}

// ---------------- GEMM BMx256 tile, 8-phase, counted vmcnt ----------------
// C[M,N] = A[M,K] @ B[N,K]^T, K=N=1024. 512 threads = 8 waves (2Mx4N).
// BM in {256,128}. XCD-affine 1-D grid remap (bijective, xcd = id%8):
//   group g = (by/CHY) + NBYC*bz; w = bx + GX*(by%CHY); id = (g%8) + 8*(w + CPG*(g/8)).
// LDS swizzle byte ^= (row&7)<<4 on stage SOURCE + ds_read (r6: conflicts = 0).
// vmcnt ledger: stageA = BM/128 loads, stageB = 2 loads; keep last 2 stages in
// flight -> vmcnt(4) for BM=256, vmcnt(3) for BM=128.
// OUTF: 0 = f16 store, 1 = f16*scale, 2 = f32 + bias
template<int OUTF, int BM>
__global__ __launch_bounds__(512, 2)
void gemm256(const f16* __restrict__ A, const f16* __restrict__ Bw,
             void* __restrict__ Cv, const float* __restrict__ bias,
             int M, long sA, long sB, long sC, float scale,
             int GX, int CHY, int NBYC, int CPG)
{
  constexpr int K = 1024, N = 1024, T = K / 64;
  constexpr int AH = BM * 64;          // bytes per A-half ((BM/2) rows x 64k x 2B)
  constexpr int BUFSZ = 2 * AH + 32768;
  constexpr int MR = BM / 64;          // m4 fragments per quadrant (4 or 2)
  constexpr int AJ = BM / 128;         // 64-row groups per A-half stage (2 or 1)
  __shared__ __align__(16) char lds[2 * BUFSZ];

  // ---- XCD-affine decode ----
  const int id = blockIdx.x;
  const int xcd = id & 7, q = id >> 3;
  const int wi = q % CPG, ghi = q / CPG;
  const int g = xcd + 8 * ghi;
  const int bchunk = g % NBYC, bz = g / NBYC;
  const int bx = wi % GX, by = bchunk * CHY + wi / GX;

  const f16* Ab = A + (long)bz * sA;
  const f16* Bb = Bw + (long)bz * sB;
  const int t = threadIdx.x;
  const int w = t >> 6, l = t & 63;
  const int wr = w >> 2, wc = w & 3;
  const int brow = by * BM, bcol = bx * 256;

  f32x4 acc[2][MR][2][2] = {};  // [mh][m4][nh][n2]

  const int srow = t >> 3;
  const int scol = ((t & 7) * 8) ^ (((t >> 3) & 7) << 3);   // f16 elements
  const int xm = (l & 7) << 4;
  const int lrow = l & 15, lslot = (l >> 4) * 16;

  auto stageA = [&](int kt, int h) {
    char* dst = lds + (kt & 1) * BUFSZ + h * AH;
    #pragma unroll
    for (int j = 0; j < AJ; ++j) {
      int ar = brow + h * (BM / 2) + j * 64 + srow;
      if (ar >= M) ar = M - 1;
      const f16* gp = Ab + (long)ar * K + kt * 64 + scol;
      __builtin_amdgcn_global_load_lds(AS1(gp), AS3(dst + j * 8192 + t * 16), 16, 0, 0);
    }
  };
  auto stageB = [&](int kt, int h) {
    char* dst = lds + (kt & 1) * BUFSZ + 2 * AH + h * 16384;
    #pragma unroll
    for (int j = 0; j < 2; ++j) {
      int br = bcol + h * 128 + j * 64 + srow;
      const f16* gp = Bb + (long)br * K + kt * 64 + scol;
      __builtin_amdgcn_global_load_lds(AS1(gp), AS3(dst + j * 8192 + t * 16), 16, 0, 0);
    }
  };
  auto ldA = [&](int kt, int mh, f16x8* a) {
    const char* base = lds + (kt & 1) * BUFSZ;
    #pragma unroll
    for (int m4 = 0; m4 < MR; ++m4)
      #pragma unroll
      for (int kk = 0; kk < 2; ++kk) {
        int rowA = mh * (BM / 2) + wr * (BM / 4) + m4 * 16 + lrow;
        int off = (rowA * 128 + kk * 64 + lslot) ^ xm;
        a[m4 * 2 + kk] = *(const f16x8*)(base + off);
      }
  };
  auto ldB = [&](int kt, int nh, f16x8* b) {
    const char* base = lds + (kt & 1) * BUFSZ + 2 * AH;
    #pragma unroll
    for (int n2 = 0; n2 < 2; ++n2)
      #pragma unroll
      for (int kk = 0; kk < 2; ++kk) {
        int rowB = nh * 128 + wc * 32 + n2 * 16 + lrow;
        int off = (rowB * 128 + kk * 64 + lslot) ^ xm;
        b[n2 * 2 + kk] = *(const f16x8*)(base + off);
      }
  };
  auto mma = [&](int mh, int nh, const f16x8* a, const f16x8* b) {
    __builtin_amdgcn_s_setprio(1);
    #pragma unroll
    for (int m4 = 0; m4 < MR; ++m4)
      #pragma unroll
      for (int n2 = 0; n2 < 2; ++n2)
        #pragma unroll
        for (int kk = 0; kk < 2; ++kk)
          acc[mh][m4][nh][n2] = __builtin_amdgcn_mfma_f32_16x16x32_f16(
              a[m4 * 2 + kk], b[n2 * 2 + kk], acc[mh][m4][nh][n2], 0, 0, 0);
    __builtin_amdgcn_s_setprio(0);
  };

  // prologue: tile0 fully + A0,B1 of tile1
  stageA(0, 0); stageA(0, 1); stageB(0, 0); stageB(0, 1);
  stageA(1, 0); stageB(1, 1);
  if constexpr (BM == 256) { VMCNT(4); } else { VMCNT(3); }
  BAR();

  f16x8 a[2 * MR], b0[4], b1[4];
  for (int kt = 0; kt < T; ++kt) {
    // phase 1: quadrant (0,0)
    ldA(kt, 0, a); ldB(kt, 0, b0);
    if (kt + 1 < T) stageA(kt + 1, 1);
    BAR();
    mma(0, 0, a, b0);
    BAR();
    // phase 2: (0,1)
    ldB(kt, 1, b1);
    if (kt + 1 < T) stageB(kt + 1, 0);
    BAR();
    mma(0, 1, a, b1);
    BAR();
    // phase 3: (1,1)
    ldA(kt, 1, a);
    if (kt + 2 < T) stageA(kt + 2, 0);
    BAR();
    mma(1, 1, a, b1);
    BAR();
    // phase 4: (1,0)
    if (kt + 2 < T) {
      stageB(kt + 2, 1);
      if constexpr (BM == 256) { VMCNT(4); } else { VMCNT(3); }
    } else if (kt + 1 < T) {
      VMCNT(0);        // final drain
    }
    BAR();
    mma(1, 0, a, b0);
    BAR();
  }

  // epilogue: C/D layout col = lane&15, row = (lane>>4)*4 + reg
  const int rj = (l >> 4) * 4;
  #pragma unroll
  for (int mh = 0; mh < 2; ++mh)
    #pragma unroll
    for (int m4 = 0; m4 < MR; ++m4)
      #pragma unroll
      for (int j = 0; j < 4; ++j) {
        const int r = brow + mh * (BM / 2) + wr * (BM / 4) + m4 * 16 + rj + j;
        if (r >= M) continue;
        #pragma unroll
        for (int nh = 0; nh < 2; ++nh)
          #pragma unroll
          for (int n2 = 0; n2 < 2; ++n2) {
            const int c = bcol + nh * 128 + wc * 32 + n2 * 16 + lrow;
            float v = acc[mh][m4][nh][n2][j];
            if constexpr (OUTF == 0) {
              ((f16*)Cv)[(long)bz * sC + (long)r * N + c] = (f16)v;
            } else if constexpr (OUTF == 1) {
              ((f16*)Cv)[(long)bz * sC + (long)r * N + c] = (f16)(v * scale);
            } else {
              ((float*)Cv)[(long)bz * sC + (long)r * N + c] = v + bias[c];
            }
          }
      }
}

// ---------------- row softmax, 1 wave/row, in-place fp16 [B*S, 1024] ----------------
__global__ __launch_bounds__(64)
void softmax_rows(f16* __restrict__ S) {
  const long row = blockIdx.x;
  f16x8* p8 = (f16x8*)(S + row * 1024);
  const int t = threadIdx.x;
  f16x8 va = p8[t], vb = p8[t + 64];
  float v[16];
  #pragma unroll
  for (int j = 0; j < 8; ++j) { v[j] = (float)va[j]; v[8 + j] = (float)vb[j]; }

  float m = v[0];
  #pragma unroll
  for (int j = 1; j < 16; ++j) m = fmaxf(m, v[j]);
  #pragma unroll
  for (int off = 1; off < 64; off <<= 1) m = fmaxf(m, __shfl_xor(m, off));

  float s = 0.f;
  #pragma unroll
  for (int j = 0; j < 16; ++j) { v[j] = __expf(v[j] - m); s += v[j]; }
  #pragma unroll
  for (int off = 1; off < 64; off <<= 1) s += __shfl_xor(s, off);
  const float inv = 1.f / s;

  f16x8 oa, ob;
  #pragma unroll
  for (int j = 0; j < 8; ++j) { oa[j] = (f16)(v[j] * inv); ob[j] = (f16)(v[8 + j] * inv); }
  p8[t] = oa; p8[t + 64] = ob;
}

// ---------------- per-batch 1024x1024 fp16 transpose ----------------
__global__ __launch_bounds__(512)
void transpose_f16(const f16* __restrict__ in, f16* __restrict__ out) {
  __shared__ f16 tile[64][65];
  const long bs = (long)blockIdx.z * 1024 * 1024;
  const int r0 = blockIdx.y * 64, c0 = blockIdx.x * 64;
  const int tx = threadIdx.x, ty = threadIdx.y;  // (64, 8)
  #pragma unroll
  for (int i = 0; i < 8; ++i)
    tile[ty + 8 * i][tx] = in[bs + (long)(r0 + ty + 8 * i) * 1024 + c0 + tx];
  __syncthreads();
  #pragma unroll
  for (int i = 0; i < 8; ++i)
    out[bs + (long)(c0 + ty + 8 * i) * 1024 + r0 + tx] = tile[tx][ty + 8 * i];
}

// ---------------- launch ----------------
extern "C" void kernel_launch(void* const* d_in, const int* in_sizes, int n_in,
                              void* d_out, int out_size, void* d_ws, size_t ws_size,
                              hipStream_t stream) {
  const float* vis = (const float*)d_in[0];
  const float* lan = (const float*)d_in[1];
  const float* Wv  = (const float*)d_in[2];
  const float* Wl  = (const float*)d_in[3];
  const float* Wo  = (const float*)d_in[4];
  const float* bo  = (const float*)d_in[5];
  float* out = (float*)d_out;

  const long PB = 1024l * 1024;
  const long SE = 16 * PB;

  f16* Ah  = (f16*)d_ws;
  f16* Xh  = Ah + SE;
  f16* Sc  = Xh + SE;
  f16* Wvh = Sc + SE;
  f16* Wlh = Wvh + PB;
  f16* Woh = Wlh + PB;
  f16* XhT = Ah;   // alias: Ah dead after projections
  f16* Att = Xh;   // alias: Xh dead after transpose+scores

  // fp32 -> fp16 conversions (division-free)
  conv_tokens2<<<dim3(1024, 16), 256, 0, stream>>>(vis, lan, Ah);
  conv_w3<<<dim3(3072), 256, 0, stream>>>(Wv, Wl, Wo, Wvh);

  // projections: X = tokens @ W^T  (GX,CHY,NBYC,CPG)
  gemm256<0, 256><<<dim3(192), 512, 0, stream>>>(Ah, Wvh, Xh, nullptr, 576, PB, 0, PB, 1.f,
                                                 4, 1, 3, 4);    // NGRP=48
  gemm256<0, 128><<<dim3(256), 512, 0, stream>>>(Ah + 576l * 1024, Wlh, Xh + 576l * 1024,
                                                 nullptr, 448, PB, 0, PB, 1.f,
                                                 4, 1, 4, 4);    // BM=128, NGRP=64
  // scores = (X @ X^T) / 32 — whole batch on one XCD (NGRP=16)
  gemm256<1, 256><<<dim3(256), 512, 0, stream>>>(Xh, Xh, Sc, nullptr, 1024, PB, PB, PB,
                                                 0.03125f, 4, 4, 1, 16);
  // transpose X for the PV step
  transpose_f16<<<dim3(16, 16, 16), dim3(64, 8), 0, stream>>>(Xh, XhT);
  // softmax rows in place (1 wave per row)
  softmax_rows<<<dim3(16 * 1024), 64, 0, stream>>>(Sc);
  // attended = P @ X — batch-affine (NGRP=16)
  gemm256<0, 256><<<dim3(256), 512, 0, stream>>>(Sc, XhT, Att, nullptr, 1024, PB, PB, PB, 1.f,
                                                 4, 4, 1, 16);
  // out = attended @ Wo^T + bo — 8 brow-panels per XCD (NGRP=8)
  gemm256<2, 256><<<dim3(256), 512, 0, stream>>>(Att, Woh, out, bo, 16384, 0, 0, 0, 1.f,
                                                 4, 8, 8, 32);
}